// Round 1
// 1612.963 us; speedup vs baseline: 1.0956x; 1.0956x over previous
//
#include <hip/hip_runtime.h>

// LIF two-layer SNN, bit-exact emulation of the f32 OpenBLAS-style reference
// (kc=320 K-blocking, sequential ascending-k f32 chains per block, block
// partials combined in order; LIF = separate f32 mul then add).
// Round 5: x4-wide gathers. Block = 256 threads, each thread owns 4
// consecutive output columns (h = 4*tid+j) -> global_load_dwordx4 per row.
// Per weight row: 4 wave-instrs on each pipe instead of 16 (ds_read/rfl/
// vmem), 4 independent fadd chains per thread hide dep latency.
// Chain add order per column is UNCHANGED -> still bit-exact.

#define T_STEPS 128
#define BATCH   512
#define NLAB    512
#define HID     1024
#define SEM     1024

// 32x32 tiled transpose, block = (32,8). R,C multiples of 32. Exact copies.
__global__ __launch_bounds__(256) void transpose32(const float* __restrict__ in,
                                                   float* __restrict__ out,
                                                   int R, int C) {
    __shared__ float tile[32][33];
    const int c0 = blockIdx.x * 32, r0 = blockIdx.y * 32;
    const int x = threadIdx.x, y0 = threadIdx.y;
#pragma unroll
    for (int i = 0; i < 32; i += 8)
        tile[y0 + i][x] = in[(size_t)(r0 + y0 + i) * C + (c0 + x)];
    __syncthreads();
#pragma unroll
    for (int i = 0; i < 32; i += 8)
        out[(size_t)(c0 + y0 + i) * R + (r0 + x)] = tile[x][y0 + i];
}

// Sequential ascending-k f32 add chains over list[lo..hi) of weight rows
// (row stride 1024 floats), 4 independent columns per thread via dwordx4,
// 8-deep load pipeline, wave-uniform scalar addressing. Per-column fadd
// order is strictly k-ascending -> bit-exact.
__device__ __forceinline__ void gather4(const int* __restrict__ list,
                                        int lo, int hi,
                                        const float* __restrict__ base, // w + 4*tid
                                        float s[4]) {
    float s0 = 0.0f, s1 = 0.0f, s2 = 0.0f, s3 = 0.0f;
    int k = lo;
    for (; k + 8 <= hi; k += 8) {
        float4 wv[8];
#pragma unroll
        for (int j = 0; j < 8; ++j) {
            const int row = __builtin_amdgcn_readfirstlane(list[k + j]);
            wv[j] = *reinterpret_cast<const float4*>(base + ((size_t)row << 10));
        }
#pragma unroll
        for (int j = 0; j < 8; ++j) {
            s0 = __fadd_rn(s0, wv[j].x);
            s1 = __fadd_rn(s1, wv[j].y);
            s2 = __fadd_rn(s2, wv[j].z);
            s3 = __fadd_rn(s3, wv[j].w);
        }
    }
    for (; k < hi; ++k) {
        const int row = __builtin_amdgcn_readfirstlane(list[k]);
        const float4 wv = *reinterpret_cast<const float4*>(base + ((size_t)row << 10));
        s0 = __fadd_rn(s0, wv.x);
        s1 = __fadd_rn(s1, wv.y);
        s2 = __fadd_rn(s2, wv.z);
        s3 = __fadd_rn(s3, wv.w);
    }
    s[0] = s0; s[1] = s1; s[2] = s2; s[3] = s3;
}

__global__ __launch_bounds__(256)
void snn_kernel(const float* __restrict__ spikes,   // (T, B, NLAB)
                const float* __restrict__ w1t,      // (NLAB, HID) = W1^T
                const float* __restrict__ w2t,      // (HID, SEM)  = W2^T
                float* __restrict__ out) {          // (B*HID) ++ (B*SEM)
    __shared__ int wc1[4];            // per-wave active counts, input spikes
    __shared__ int wc1p;              // partial: active k in [256,320) (wave 2, l<32)
    __shared__ int wc2[4];            // per-wave spike counts, layer 1
    __shared__ int wc2p[3];           // partials at h=320 (w1,l<16), 640 (w2,l<32), 960 (w3,l<48)
    __shared__ __align__(16) int list1[NLAB];   // ascending active inputs
    __shared__ __align__(16) int list2[HID];    // ascending spiking hidden

    const int b    = blockIdx.x;
    const int tid  = threadIdx.x;               // 0..255
    const int w    = tid >> 6;                  // wave 0..3
    const int lane = tid & 63;
    const unsigned long long below = (1ull << lane) - 1ull;

    float v1[4] = {0.0f, 0.0f, 0.0f, 0.0f};
    float v2[4] = {0.0f, 0.0f, 0.0f, 0.0f};
    int   c1[4] = {0, 0, 0, 0};
    int   c2[4] = {0, 0, 0, 0};

    // thread covers inputs k = 2*tid, 2*tid+1 and output columns 4*tid..4*tid+3
    const float* sp_b = spikes + (size_t)b * NLAB + 2 * tid;
    const float* w1b  = w1t + 4 * tid;
    const float* w2b  = w2t + 4 * tid;

    for (int t = 0; t < T_STEPS; ++t) {
        // ---- stage 1a: ballots + per-wave counts of active inputs ----
        const float2 sv = *reinterpret_cast<const float2*>(sp_b + (size_t)t * (BATCH * NLAB));
        const bool a0 = (sv.x != 0.0f);
        const bool a1 = (sv.y != 0.0f);
        const unsigned long long m0 = __ballot(a0);
        const unsigned long long m1 = __ballot(a1);
        if (lane == 0) {
            wc1[w] = __popcll(m0) + __popcll(m1);
            if (w == 2)   // k = 256 + 2*l + j ; k < 320 <=> l < 32
                wc1p = __popcll(m0 & 0xFFFFFFFFull) + __popcll(m1 & 0xFFFFFFFFull);
        }
        const int pre1 = __popcll(m0 & below) + __popcll(m1 & below);
        __syncthreads();                        // wc1 ready; prev stage-3 done

        // ---- stage 1b: deterministic ascending compaction (lex (lane,j) = asc k) ----
        {
            int base = 0;
            for (int i = 0; i < w; ++i) base += wc1[i];
            int p = base + pre1;
            if (a0) list1[p++] = 2 * tid;
            if (a1) list1[p]   = 2 * tid + 1;
        }
        __syncthreads();                        // list1 ready

        // ---- stage 2: layer 1, h = 4*tid+j. kc blocks [0,320),[320,512) ----
        bool spk0, spk1, spk2, spk3;
        int  preh;
        {
            const int nA = wc1[0] + wc1[1] + wc1p;
            const int n1 = wc1[0] + wc1[1] + wc1[2] + wc1[3];
            float xA[4], xB[4];
            gather4(list1, 0,  nA, w1b, xA);
            gather4(list1, nA, n1, w1b, xB);
#pragma unroll
            for (int j = 0; j < 4; ++j) {
                const float x1 = __fadd_rn(xA[j], xB[j]);
                v1[j] = __fadd_rn(__fmul_rn(0.95f, v1[j]), x1);
            }
            spk0 = (v1[0] > 1.0f); if (spk0) { c1[0]++; v1[0] = 0.0f; }
            spk1 = (v1[1] > 1.0f); if (spk1) { c1[1]++; v1[1] = 0.0f; }
            spk2 = (v1[2] > 1.0f); if (spk2) { c1[2]++; v1[2] = 0.0f; }
            spk3 = (v1[3] > 1.0f); if (spk3) { c1[3]++; v1[3] = 0.0f; }

            const unsigned long long b0 = __ballot(spk0);
            const unsigned long long b1 = __ballot(spk1);
            const unsigned long long b2 = __ballot(spk2);
            const unsigned long long b3 = __ballot(spk3);
            if (lane == 0) {
                wc2[w] = __popcll(b0) + __popcll(b1) + __popcll(b2) + __popcll(b3);
                // h = 256*w + 4*l + j ; boundaries 320/640/960 -> l<16 / l<32 / l<48
                if (w == 1)
                    wc2p[0] = __popcll(b0 & 0xFFFFull) + __popcll(b1 & 0xFFFFull)
                            + __popcll(b2 & 0xFFFFull) + __popcll(b3 & 0xFFFFull);
                if (w == 2)
                    wc2p[1] = __popcll(b0 & 0xFFFFFFFFull) + __popcll(b1 & 0xFFFFFFFFull)
                            + __popcll(b2 & 0xFFFFFFFFull) + __popcll(b3 & 0xFFFFFFFFull);
                if (w == 3)
                    wc2p[2] = __popcll(b0 & 0xFFFFFFFFFFFFull) + __popcll(b1 & 0xFFFFFFFFFFFFull)
                            + __popcll(b2 & 0xFFFFFFFFFFFFull) + __popcll(b3 & 0xFFFFFFFFFFFFull);
            }
            preh = __popcll(b0 & below) + __popcll(b1 & below)
                 + __popcll(b2 & below) + __popcll(b3 & below);
        }
        __syncthreads();                        // wc2 ready

        {
            int base = 0;
            for (int i = 0; i < w; ++i) base += wc2[i];
            int p = base + preh;                // own-lane entries consecutive, j asc
            if (spk0) list2[p++] = 4 * tid;
            if (spk1) list2[p++] = 4 * tid + 1;
            if (spk2) list2[p++] = 4 * tid + 2;
            if (spk3) list2[p]   = 4 * tid + 3;
        }
        __syncthreads();                        // list2 ready

        // ---- stage 3: layer 2, s = 4*tid+j. kc blocks 320/320/320/64 ----
        {
            const int nA = wc2[0] + wc2p[0];
            const int nB = wc2[0] + wc2[1] + wc2p[1];
            const int nC = wc2[0] + wc2[1] + wc2[2] + wc2p[2];
            const int n2 = wc2[0] + wc2[1] + wc2[2] + wc2[3];
            float t1[4], t2[4], t3[4], t4[4];
            gather4(list2, 0,  nA, w2b, t1);
            gather4(list2, nA, nB, w2b, t2);
            gather4(list2, nB, nC, w2b, t3);
            gather4(list2, nC, n2, w2b, t4);
#pragma unroll
            for (int j = 0; j < 4; ++j) {
                const float x2 = __fadd_rn(__fadd_rn(__fadd_rn(t1[j], t2[j]), t3[j]), t4[j]);
                v2[j] = __fadd_rn(__fmul_rn(0.95f, v2[j]), x2);
                if (v2[j] > 1.0f) { c2[j]++; v2[j] = 0.0f; }
            }
        }
        __syncthreads();                        // list2/wc2 free for next iter
    }

    const float sc = 1.0f / 128.0f;
    const float4 o1 = make_float4((float)c1[0] * sc, (float)c1[1] * sc,
                                  (float)c1[2] * sc, (float)c1[3] * sc);
    *reinterpret_cast<float4*>(out + (size_t)b * HID + 4 * tid) = o1;
    const float4 o2 = make_float4((float)c2[0] * sc, (float)c2[1] * sc,
                                  (float)c2[2] * sc, (float)c2[3] * sc);
    *reinterpret_cast<float4*>(out + (size_t)BATCH * HID + (size_t)b * SEM + 4 * tid) = o2;
}

extern "C" void kernel_launch(void* const* d_in, const int* in_sizes, int n_in,
                              void* d_out, int out_size, void* d_ws, size_t ws_size,
                              hipStream_t stream) {
    const float* spikes = (const float*)d_in[0];  // (128, 512, 512)
    const float* W1     = (const float*)d_in[1];  // (1024, 512)
    const float* W2     = (const float*)d_in[2];  // (1024, 1024)
    float* out = (float*)d_out;

    float* w1t = (float*)d_ws;                    // (512, 1024)
    float* w2t = w1t + (size_t)NLAB * HID;        // (1024, 1024) — 6 MB total

    dim3 tb(32, 8);
    transpose32<<<dim3(NLAB / 32, HID / 32), tb, 0, stream>>>(W1, w1t, HID, NLAB);
    transpose32<<<dim3(HID / 32, SEM / 32),  tb, 0, stream>>>(W2, w2t, SEM, HID);

    snn_kernel<<<BATCH, 256, 0, stream>>>(spikes, w1t, w2t, out);
}

// Round 2
// 1564.395 us; speedup vs baseline: 1.1297x; 1.0310x over previous
//
#include <hip/hip_runtime.h>

// LIF two-layer SNN, bit-exact emulation of the f32 OpenBLAS-style reference
// (kc=320 K-blocking, sequential ascending-k f32 chains per block, block
// partials combined in order; LIF = separate f32 mul then add).
// Round 6: L2-roofline falsification probe. Round-5 measured 33.8 TB/s of
// L2 gather traffic = 98% of the 34.5 TB/s ceiling. This version deepens the
// gather pipeline to 16 float4-loads in flight and hoists the next-timestep
// spike load to overlap stage-2/3 compute. Chain add order UNCHANGED ->
// bit-exact. Prediction: null (+-3%) if L2-BW-bound; >5% gain falsifies.

#define T_STEPS 128
#define BATCH   512
#define NLAB    512
#define HID     1024
#define SEM     1024

// 32x32 tiled transpose, block = (32,8). R,C multiples of 32. Exact copies.
__global__ __launch_bounds__(256) void transpose32(const float* __restrict__ in,
                                                   float* __restrict__ out,
                                                   int R, int C) {
    __shared__ float tile[32][33];
    const int c0 = blockIdx.x * 32, r0 = blockIdx.y * 32;
    const int x = threadIdx.x, y0 = threadIdx.y;
#pragma unroll
    for (int i = 0; i < 32; i += 8)
        tile[y0 + i][x] = in[(size_t)(r0 + y0 + i) * C + (c0 + x)];
    __syncthreads();
#pragma unroll
    for (int i = 0; i < 32; i += 8)
        out[(size_t)(c0 + y0 + i) * R + (r0 + x)] = tile[x][y0 + i];
}

// Sequential ascending-k f32 add chains over list[lo..hi) of weight rows
// (row stride 1024 floats), 4 independent columns per thread via dwordx4,
// 16-deep load pipeline, wave-uniform scalar addressing. Per-column fadd
// order is strictly k-ascending -> bit-exact.
__device__ __forceinline__ void gather4(const int* __restrict__ list,
                                        int lo, int hi,
                                        const float* __restrict__ base, // w + 4*tid
                                        float s[4]) {
    float s0 = 0.0f, s1 = 0.0f, s2 = 0.0f, s3 = 0.0f;
    int k = lo;
    for (; k + 16 <= hi; k += 16) {
        float4 wv[16];
#pragma unroll
        for (int j = 0; j < 16; ++j) {
            const int row = __builtin_amdgcn_readfirstlane(list[k + j]);
            wv[j] = *reinterpret_cast<const float4*>(base + ((size_t)row << 10));
        }
#pragma unroll
        for (int j = 0; j < 16; ++j) {
            s0 = __fadd_rn(s0, wv[j].x);
            s1 = __fadd_rn(s1, wv[j].y);
            s2 = __fadd_rn(s2, wv[j].z);
            s3 = __fadd_rn(s3, wv[j].w);
        }
    }
    for (; k + 8 <= hi; k += 8) {
        float4 wv[8];
#pragma unroll
        for (int j = 0; j < 8; ++j) {
            const int row = __builtin_amdgcn_readfirstlane(list[k + j]);
            wv[j] = *reinterpret_cast<const float4*>(base + ((size_t)row << 10));
        }
#pragma unroll
        for (int j = 0; j < 8; ++j) {
            s0 = __fadd_rn(s0, wv[j].x);
            s1 = __fadd_rn(s1, wv[j].y);
            s2 = __fadd_rn(s2, wv[j].z);
            s3 = __fadd_rn(s3, wv[j].w);
        }
    }
    for (; k < hi; ++k) {
        const int row = __builtin_amdgcn_readfirstlane(list[k]);
        const float4 wv = *reinterpret_cast<const float4*>(base + ((size_t)row << 10));
        s0 = __fadd_rn(s0, wv.x);
        s1 = __fadd_rn(s1, wv.y);
        s2 = __fadd_rn(s2, wv.z);
        s3 = __fadd_rn(s3, wv.w);
    }
    s[0] = s0; s[1] = s1; s[2] = s2; s[3] = s3;
}

__global__ __launch_bounds__(256)
void snn_kernel(const float* __restrict__ spikes,   // (T, B, NLAB)
                const float* __restrict__ w1t,      // (NLAB, HID) = W1^T
                const float* __restrict__ w2t,      // (HID, SEM)  = W2^T
                float* __restrict__ out) {          // (B*HID) ++ (B*SEM)
    __shared__ int wc1[4];            // per-wave active counts, input spikes
    __shared__ int wc1p;              // partial: active k in [256,320) (wave 2, l<32)
    __shared__ int wc2[4];            // per-wave spike counts, layer 1
    __shared__ int wc2p[3];           // partials at h=320 (w1,l<16), 640 (w2,l<32), 960 (w3,l<48)
    __shared__ __align__(16) int list1[NLAB];   // ascending active inputs
    __shared__ __align__(16) int list2[HID];    // ascending spiking hidden

    const int b    = blockIdx.x;
    const int tid  = threadIdx.x;               // 0..255
    const int w    = tid >> 6;                  // wave 0..3
    const int lane = tid & 63;
    const unsigned long long below = (1ull << lane) - 1ull;

    float v1[4] = {0.0f, 0.0f, 0.0f, 0.0f};
    float v2[4] = {0.0f, 0.0f, 0.0f, 0.0f};
    int   c1[4] = {0, 0, 0, 0};
    int   c2[4] = {0, 0, 0, 0};

    // thread covers inputs k = 2*tid, 2*tid+1 and output columns 4*tid..4*tid+3
    const float* sp_b = spikes + (size_t)b * NLAB + 2 * tid;
    const float* w1b  = w1t + 4 * tid;
    const float* w2b  = w2t + 4 * tid;

    // prefetch spikes for t=0
    float2 sv = *reinterpret_cast<const float2*>(sp_b);

    for (int t = 0; t < T_STEPS; ++t) {
        // ---- stage 1a: ballots + per-wave counts of active inputs ----
        const bool a0 = (sv.x != 0.0f);
        const bool a1 = (sv.y != 0.0f);
        const unsigned long long m0 = __ballot(a0);
        const unsigned long long m1 = __ballot(a1);
        if (lane == 0) {
            wc1[w] = __popcll(m0) + __popcll(m1);
            if (w == 2)   // k = 256 + 2*l + j ; k < 320 <=> l < 32
                wc1p = __popcll(m0 & 0xFFFFFFFFull) + __popcll(m1 & 0xFFFFFFFFull);
        }
        const int pre1 = __popcll(m0 & below) + __popcll(m1 & below);
        __syncthreads();                        // wc1 ready; prev stage-3 done

        // ---- stage 1b: deterministic ascending compaction (lex (lane,j) = asc k) ----
        {
            int base = 0;
            for (int i = 0; i < w; ++i) base += wc1[i];
            int p = base + pre1;
            if (a0) list1[p++] = 2 * tid;
            if (a1) list1[p]   = 2 * tid + 1;
        }
        __syncthreads();                        // list1 ready

        // prefetch spikes for t+1; overlaps stage-2/3 gather compute
        if (t + 1 < T_STEPS)
            sv = *reinterpret_cast<const float2*>(sp_b + (size_t)(t + 1) * (BATCH * NLAB));

        // ---- stage 2: layer 1, h = 4*tid+j. kc blocks [0,320),[320,512) ----
        bool spk0, spk1, spk2, spk3;
        int  preh;
        {
            const int nA = wc1[0] + wc1[1] + wc1p;
            const int n1 = wc1[0] + wc1[1] + wc1[2] + wc1[3];
            float xA[4], xB[4];
            gather4(list1, 0,  nA, w1b, xA);
            gather4(list1, nA, n1, w1b, xB);
#pragma unroll
            for (int j = 0; j < 4; ++j) {
                const float x1 = __fadd_rn(xA[j], xB[j]);
                v1[j] = __fadd_rn(__fmul_rn(0.95f, v1[j]), x1);
            }
            spk0 = (v1[0] > 1.0f); if (spk0) { c1[0]++; v1[0] = 0.0f; }
            spk1 = (v1[1] > 1.0f); if (spk1) { c1[1]++; v1[1] = 0.0f; }
            spk2 = (v1[2] > 1.0f); if (spk2) { c1[2]++; v1[2] = 0.0f; }
            spk3 = (v1[3] > 1.0f); if (spk3) { c1[3]++; v1[3] = 0.0f; }

            const unsigned long long b0 = __ballot(spk0);
            const unsigned long long b1 = __ballot(spk1);
            const unsigned long long b2 = __ballot(spk2);
            const unsigned long long b3 = __ballot(spk3);
            if (lane == 0) {
                wc2[w] = __popcll(b0) + __popcll(b1) + __popcll(b2) + __popcll(b3);
                // h = 256*w + 4*l + j ; boundaries 320/640/960 -> l<16 / l<32 / l<48
                if (w == 1)
                    wc2p[0] = __popcll(b0 & 0xFFFFull) + __popcll(b1 & 0xFFFFull)
                            + __popcll(b2 & 0xFFFFull) + __popcll(b3 & 0xFFFFull);
                if (w == 2)
                    wc2p[1] = __popcll(b0 & 0xFFFFFFFFull) + __popcll(b1 & 0xFFFFFFFFull)
                            + __popcll(b2 & 0xFFFFFFFFull) + __popcll(b3 & 0xFFFFFFFFull);
                if (w == 3)
                    wc2p[2] = __popcll(b0 & 0xFFFFFFFFFFFFull) + __popcll(b1 & 0xFFFFFFFFFFFFull)
                            + __popcll(b2 & 0xFFFFFFFFFFFFull) + __popcll(b3 & 0xFFFFFFFFFFFFull);
            }
            preh = __popcll(b0 & below) + __popcll(b1 & below)
                 + __popcll(b2 & below) + __popcll(b3 & below);
        }
        __syncthreads();                        // wc2 ready

        {
            int base = 0;
            for (int i = 0; i < w; ++i) base += wc2[i];
            int p = base + preh;                // own-lane entries consecutive, j asc
            if (spk0) list2[p++] = 4 * tid;
            if (spk1) list2[p++] = 4 * tid + 1;
            if (spk2) list2[p++] = 4 * tid + 2;
            if (spk3) list2[p]   = 4 * tid + 3;
        }
        __syncthreads();                        // list2 ready

        // ---- stage 3: layer 2, s = 4*tid+j. kc blocks 320/320/320/64 ----
        {
            const int nA = wc2[0] + wc2p[0];
            const int nB = wc2[0] + wc2[1] + wc2p[1];
            const int nC = wc2[0] + wc2[1] + wc2[2] + wc2p[2];
            const int n2 = wc2[0] + wc2[1] + wc2[2] + wc2[3];
            float t1[4], t2[4], t3[4], t4[4];
            gather4(list2, 0,  nA, w2b, t1);
            gather4(list2, nA, nB, w2b, t2);
            gather4(list2, nB, nC, w2b, t3);
            gather4(list2, nC, n2, w2b, t4);
#pragma unroll
            for (int j = 0; j < 4; ++j) {
                const float x2 = __fadd_rn(__fadd_rn(__fadd_rn(t1[j], t2[j]), t3[j]), t4[j]);
                v2[j] = __fadd_rn(__fmul_rn(0.95f, v2[j]), x2);
                if (v2[j] > 1.0f) { c2[j]++; v2[j] = 0.0f; }
            }
        }
        __syncthreads();                        // list2/wc2 free for next iter
    }

    const float sc = 1.0f / 128.0f;
    const float4 o1 = make_float4((float)c1[0] * sc, (float)c1[1] * sc,
                                  (float)c1[2] * sc, (float)c1[3] * sc);
    *reinterpret_cast<float4*>(out + (size_t)b * HID + 4 * tid) = o1;
    const float4 o2 = make_float4((float)c2[0] * sc, (float)c2[1] * sc,
                                  (float)c2[2] * sc, (float)c2[3] * sc);
    *reinterpret_cast<float4*>(out + (size_t)BATCH * HID + (size_t)b * SEM + 4 * tid) = o2;
}

extern "C" void kernel_launch(void* const* d_in, const int* in_sizes, int n_in,
                              void* d_out, int out_size, void* d_ws, size_t ws_size,
                              hipStream_t stream) {
    const float* spikes = (const float*)d_in[0];  // (128, 512, 512)
    const float* W1     = (const float*)d_in[1];  // (1024, 512)
    const float* W2     = (const float*)d_in[2];  // (1024, 1024)
    float* out = (float*)d_out;

    float* w1t = (float*)d_ws;                    // (512, 1024)
    float* w2t = w1t + (size_t)NLAB * HID;        // (1024, 1024) — 6 MB total

    dim3 tb(32, 8);
    transpose32<<<dim3(NLAB / 32, HID / 32), tb, 0, stream>>>(W1, w1t, HID, NLAB);
    transpose32<<<dim3(HID / 32, SEM / 32),  tb, 0, stream>>>(W2, w2t, SEM, HID);

    snn_kernel<<<BATCH, 256, 0, stream>>>(spikes, w1t, w2t, out);
}